// Round 3
// baseline (3194.018 us; speedup 1.0000x reference)
//
#include <hip/hip_runtime.h>

#define NPIX 65536
#define SSTR 134

// float workspace offsets (in floats)
#define OFF_W1T 0
#define OFF_W2T 36864
#define OFF_RED 73728
#define RED_KSUM 0
#define RED_VSUM 512
#define RED_AGG 1024
#define PREP_TOTAL 107520

__device__ __forceinline__ float b2f(unsigned short u) {
  union { unsigned int i; float f; } z; z.i = ((unsigned int)u) << 16; return z.f;
}
__device__ __forceinline__ unsigned short f2b(float f) {
  union { float f; unsigned int i; } z; z.f = f;
  unsigned int r = z.i + 0x7fffu + ((z.i >> 16) & 1u);
  return (unsigned short)(r >> 16);
}
__device__ __forceinline__ float lo16(unsigned int u) {
  union { unsigned int i; float f; } z; z.i = u << 16; return z.f;
}
__device__ __forceinline__ float hi16(unsigned int u) {
  union { unsigned int i; float f; } z; z.i = u & 0xffff0000u; return z.f;
}

// Transpose conv weights to [c][o][9] for contiguous uniform loads; zero the
// reduction region (d_ws is 0xAA-poisoned before every call).
__global__ __launch_bounds__(256) void prep_kernel(
    const float* __restrict__ W1, const float* __restrict__ W2,
    float* __restrict__ wf)
{
  int i = blockIdx.x * 256 + threadIdx.x;
  if (i >= PREP_TOTAL) return;
  float v;
  if (i < OFF_W2T) {
    int j = i;           int c = j / 576; int r = j % 576; int o = r / 9; int t = r % 9;
    v = W1[o * 576 + c * 9 + t];          // W1t[c][o][t]
  } else if (i < OFF_RED) {
    int j = i - OFF_W2T; int c = j / 576; int r = j % 576; int o = r / 9; int t = r % 9;
    v = W2[o * 576 + c * 9 + t];
  } else v = 0.0f;
  wf[i] = v;
}

// Pass 1: per-pixel Q/K/V (1x1 conv), L2-normalize Q,K; write Qn (bf16);
// accumulate k_sum, value_sum, agg_kv via LDS staging + global fp32 atomics.
__global__ __launch_bounds__(128) void qkv_kernel(
    const float* __restrict__ x,
    const float* __restrict__ Wq, const float* __restrict__ bq,
    const float* __restrict__ Wk, const float* __restrict__ bk,
    const float* __restrict__ Wv, const float* __restrict__ bv,
    unsigned short* __restrict__ Qn, float* __restrict__ red)
{
  __shared__ unsigned short sk[64 * SSTR];
  __shared__ unsigned short sv[64 * SSTR];
  const int b = blockIdx.y;
  const int t = threadIdx.x;
  const int ok0 = (t >> 3) << 2;   // 16 groups x 4 rows
  const int ov0 = (t & 7) << 3;    // 8 groups x 8 cols
  float agg[4][8];
#pragma unroll
  for (int i2 = 0; i2 < 4; ++i2)
#pragma unroll
    for (int j2 = 0; j2 < 8; ++j2) agg[i2][j2] = 0.f;
  float rsum = 0.f;

  for (int it = 0; it < 4; ++it) {
    const int n = (blockIdx.x << 9) + (it << 7) + t;
    const size_t base = (size_t)b * 64 * NPIX + n;
    float xv[64];
#pragma unroll
    for (int c = 0; c < 64; ++c) xv[c] = x[base + (size_t)c * NPIX];

#define MATVEC_STAGE(W, B, DST, SS)                                            \
    {                                                                          \
      SS = 0.f;                                                                \
      for (int o = 0; o < 64; o += 4) {                                        \
        float a0 = (B)[o],     a1 = (B)[o + 1];                                \
        float a2 = (B)[o + 2], a3 = (B)[o + 3];                                \
        _Pragma("unroll")                                                      \
        for (int c = 0; c < 64; ++c) {                                         \
          const float xc = xv[c];                                              \
          a0 = fmaf((W)[(o    ) * 64 + c], xc, a0);                            \
          a1 = fmaf((W)[(o + 1) * 64 + c], xc, a1);                            \
          a2 = fmaf((W)[(o + 2) * 64 + c], xc, a2);                            \
          a3 = fmaf((W)[(o + 3) * 64 + c], xc, a3);                            \
        }                                                                      \
        DST[(o    ) * SSTR + t] = f2b(a0);                                     \
        DST[(o + 1) * SSTR + t] = f2b(a1);                                     \
        DST[(o + 2) * SSTR + t] = f2b(a2);                                     \
        DST[(o + 3) * SSTR + t] = f2b(a3);                                     \
        SS = fmaf(a0, a0, SS); SS = fmaf(a1, a1, SS);                          \
        SS = fmaf(a2, a2, SS); SS = fmaf(a3, a3, SS);                          \
      }                                                                        \
    }

    float ssq, ssk, ssv;
    // Q staged into sv temporarily (own column), normalized, written to global
    MATVEC_STAGE(Wq, bq, sv, ssq);
    {
      const float rn = rsqrtf(ssq);
      for (int o = 0; o < 64; ++o)
        Qn[base + (size_t)o * NPIX] = f2b(b2f(sv[o * SSTR + t]) * rn);
    }
    // K staged into sk, normalized in place (own column only)
    MATVEC_STAGE(Wk, bk, sk, ssk);
    {
      const float rn = rsqrtf(ssk);
      for (int o = 0; o < 64; ++o)
        sk[o * SSTR + t] = f2b(b2f(sk[o * SSTR + t]) * rn);
    }
    // V staged into sv (overwrites Q staging; own column only)
    MATVEC_STAGE(Wv, bv, sv, ssv);
    (void)ssv;
    __syncthreads();
    // k_sum (wave 0) / value_sum (wave 1) partials
    {
      const unsigned short* row = (t < 64) ? (sk + t * SSTR) : (sv + (t - 64) * SSTR);
      float s2 = 0.f;
      for (int p = 0; p < 128; p += 2) {
        unsigned int u = *(const unsigned int*)(row + p);
        s2 += lo16(u) + hi16(u);
      }
      rsum += s2;
    }
    // agg_kv partial: each thread owns a 4x8 block of the 64x64 output
    for (int p = 0; p < 128; p += 2) {
      float k0[4], k1[4], v0[8], v1[8];
#pragma unroll
      for (int i2 = 0; i2 < 4; ++i2) {
        unsigned int u = *(const unsigned int*)(sk + (ok0 + i2) * SSTR + p);
        k0[i2] = lo16(u); k1[i2] = hi16(u);
      }
#pragma unroll
      for (int j2 = 0; j2 < 8; ++j2) {
        unsigned int u = *(const unsigned int*)(sv + (ov0 + j2) * SSTR + p);
        v0[j2] = lo16(u); v1[j2] = hi16(u);
      }
#pragma unroll
      for (int i2 = 0; i2 < 4; ++i2)
#pragma unroll
        for (int j2 = 0; j2 < 8; ++j2) {
          agg[i2][j2] = fmaf(k0[i2], v0[j2], agg[i2][j2]);
          agg[i2][j2] = fmaf(k1[i2], v1[j2], agg[i2][j2]);
        }
    }
    __syncthreads();
  }
  if (t < 64) atomicAdd(red + RED_KSUM + b * 64 + t, rsum);
  else        atomicAdd(red + RED_VSUM + b * 64 + (t - 64), rsum);
  float* aggb = red + RED_AGG + b * 4096;
#pragma unroll
  for (int i2 = 0; i2 < 4; ++i2)
#pragma unroll
    for (int j2 = 0; j2 < 8; ++j2)
      atomicAdd(aggb + (ok0 + i2) * 64 + (ov0 + j2), agg[i2][j2]);
}

// Pass 2: per pixel: denom, numerator = vsum + agg^T qn, *denom, then Wr 1x1.
__global__ __launch_bounds__(256) void attn_kernel(
    const unsigned short* __restrict__ Qn,
    const float* __restrict__ Wr, const float* __restrict__ br,
    const float* __restrict__ red, unsigned short* __restrict__ attn)
{
  __shared__ unsigned short swv[64 * 260];
  const int b = blockIdx.y;
  const int t = threadIdx.x;
  const int n = blockIdx.x * 256 + t;
  const size_t base = (size_t)b * 64 * NPIX + n;
  const float* ks  = red + RED_KSUM + b * 64;
  const float* vs  = red + RED_VSUM + b * 64;
  const float* agg = red + RED_AGG + b * 4096;
  float qn[64];
  float s = 0.f;
#pragma unroll
  for (int ok = 0; ok < 64; ++ok) {
    qn[ok] = b2f(Qn[base + (size_t)ok * NPIX]);
    s = fmaf(qn[ok], ks[ok] + 1e-6f, s);
  }
  const float denom = 1.0f / (65536.0f + s);
  for (int ov = 0; ov < 64; ov += 4) {
    float a0 = vs[ov], a1 = vs[ov + 1], a2 = vs[ov + 2], a3 = vs[ov + 3];
#pragma unroll
    for (int ok = 0; ok < 64; ++ok) {
      const float qq = qn[ok];
      a0 = fmaf(agg[ok * 64 + ov    ], qq, a0);
      a1 = fmaf(agg[ok * 64 + ov + 1], qq, a1);
      a2 = fmaf(agg[ok * 64 + ov + 2], qq, a2);
      a3 = fmaf(agg[ok * 64 + ov + 3], qq, a3);
    }
    swv[(ov    ) * 260 + t] = f2b(a0 * denom);
    swv[(ov + 1) * 260 + t] = f2b(a1 * denom);
    swv[(ov + 2) * 260 + t] = f2b(a2 * denom);
    swv[(ov + 3) * 260 + t] = f2b(a3 * denom);
  }
  // own-column round-trip: no barrier needed
  float wvr[64];
#pragma unroll
  for (int ov = 0; ov < 64; ++ov) wvr[ov] = b2f(swv[ov * 260 + t]);
  for (int o = 0; o < 64; o += 4) {
    float a0 = br[o],     a1 = br[o + 1];
    float a2 = br[o + 2], a3 = br[o + 3];
#pragma unroll
    for (int ov = 0; ov < 64; ++ov) {
      const float wv = wvr[ov];
      a0 = fmaf(Wr[(o    ) * 64 + ov], wv, a0);
      a1 = fmaf(Wr[(o + 1) * 64 + ov], wv, a1);
      a2 = fmaf(Wr[(o + 2) * 64 + ov], wv, a2);
      a3 = fmaf(Wr[(o + 3) * 64 + ov], wv, a3);
    }
    attn[base + (size_t)(o    ) * NPIX] = f2b(a0);
    attn[base + (size_t)(o + 1) * NPIX] = f2b(a1);
    attn[base + (size_t)(o + 2) * NPIX] = f2b(a2);
    attn[base + (size_t)(o + 3) * NPIX] = f2b(a3);
  }
}

// 3x3 SAME conv, 64->64 channels. FUSE=false: bf16 out (scratch).
// FUSE=true: fused `*x + x` epilogue, fp32 out (final d_out — reference
// output dtype is float32).
template <bool FUSE>
__global__ __launch_bounds__(256) void conv3_kernel(
    const unsigned short* __restrict__ in, const float* __restrict__ wt,
    const float* __restrict__ bias, const float* __restrict__ xin,
    void* __restrict__ outv)
{
  __shared__ unsigned short tile[64 * 6 * 66];
  const int b = blockIdx.z;
  const int ty0 = blockIdx.y << 2;
  const int tx0 = blockIdx.x << 6;
  const int tid = threadIdx.x;
  const size_t cbase = (size_t)b * 64 * NPIX;
  for (int s = tid; s < 64 * 6 * 66; s += 256) {
    const int xx = s % 66;
    const int r0 = s / 66;
    const int yy = r0 % 6;
    const int c  = r0 / 6;
    const int gx = tx0 + xx - 1;
    const int gy = ty0 + yy - 1;
    unsigned short v = 0;
    if ((unsigned)gx < 256u && (unsigned)gy < 256u)
      v = in[cbase + (size_t)c * NPIX + (gy << 8) + gx];
    tile[s] = v;
  }
  __syncthreads();
  const int lx = tid & 63;
  const int ly = tid >> 6;
  float acc[64];
#pragma unroll
  for (int o = 0; o < 64; ++o) acc[o] = bias[o];
  for (int c = 0; c < 64; ++c) {
    const unsigned short* tc = tile + c * 396 + ly * 66 + lx;
    float nb[9];
#pragma unroll
    for (int dy = 0; dy < 3; ++dy)
#pragma unroll
      for (int dx = 0; dx < 3; ++dx) nb[dy * 3 + dx] = b2f(tc[dy * 66 + dx]);
    const float* wc = wt + c * 576;   // W_t[c][o][9], contiguous -> uniform bursts
#pragma unroll
    for (int o = 0; o < 64; ++o) {
      float a = acc[o];
#pragma unroll
      for (int t2 = 0; t2 < 9; ++t2) a = fmaf(wc[o * 9 + t2], nb[t2], a);
      acc[o] = a;
    }
  }
  const int gx = tx0 + lx;
  const int gy = ty0 + ly;
  const size_t pbase = cbase + (size_t)(gy << 8) + gx;
#pragma unroll
  for (int o = 0; o < 64; ++o) {
    const size_t idx = pbase + (size_t)o * NPIX;
    if (FUSE) {
      const float xo = xin[idx];
      ((float*)outv)[idx] = fmaf(acc[o], xo, xo);   // conv2 * x + x, fp32 out
    } else {
      ((unsigned short*)outv)[idx] = f2b(acc[o]);
    }
  }
}

extern "C" void kernel_launch(void* const* d_in, const int* in_sizes, int n_in,
                              void* d_out, int out_size, void* d_ws, size_t ws_size,
                              hipStream_t stream) {
  (void)in_sizes; (void)n_in; (void)out_size; (void)ws_size;
  const float* x  = (const float*)d_in[0];
  const float* Wq = (const float*)d_in[1];
  const float* bq = (const float*)d_in[2];
  const float* Wk = (const float*)d_in[3];
  const float* bk = (const float*)d_in[4];
  const float* Wv = (const float*)d_in[5];
  const float* bv = (const float*)d_in[6];
  const float* Wr = (const float*)d_in[7];
  const float* br = (const float*)d_in[8];
  const float* W1 = (const float*)d_in[9];
  const float* b1 = (const float*)d_in[10];
  const float* W2 = (const float*)d_in[11];
  const float* b2 = (const float*)d_in[12];

  float* wf  = (float*)d_ws;
  float* red = wf + OFF_RED;
  // bufA (bf16, 67MB) lives in ws past the weight/red region. bufB (bf16
  // attn scratch) aliases the first half of d_out (d_out is 134MB of fp32);
  // conv1 fully consumes it before conv2 overwrites d_out with the final
  // fp32 result (stream-serialized).
  unsigned short* bufA = (unsigned short*)((char*)d_ws + (512u * 1024u));
  unsigned short* bufB = (unsigned short*)d_out;

  prep_kernel<<<(PREP_TOTAL + 255) / 256, 256, 0, stream>>>(W1, W2, wf);
  qkv_kernel<<<dim3(128, 8), 128, 0, stream>>>(x, Wq, bq, Wk, bk, Wv, bv, bufA, red);
  attn_kernel<<<dim3(256, 8), 256, 0, stream>>>(bufA, Wr, br, red, bufB);
  conv3_kernel<false><<<dim3(4, 64, 8), 256, 0, stream>>>(
      bufB, wf + OFF_W1T, b1, nullptr, bufA);
  conv3_kernel<true><<<dim3(4, 64, 8), 256, 0, stream>>>(
      bufA, wf + OFF_W2T, b2, x, d_out);
}

// Round 4
// 1361.617 us; speedup vs baseline: 2.3458x; 2.3458x over previous
//
#include <hip/hip_runtime.h>

typedef __attribute__((ext_vector_type(8))) short short8;
typedef __attribute__((ext_vector_type(4))) float f32x4;

#define NPIX 65536
#define SSTR 134
#define RED_KSUM 0
#define RED_VSUM 512
#define RED_AGG 1024

__device__ __forceinline__ float b2f(unsigned short u) {
  union { unsigned int i; float f; } z; z.i = ((unsigned int)u) << 16; return z.f;
}
__device__ __forceinline__ unsigned short f2b(float f) {
  union { float f; unsigned int i; } z; z.f = f;
  unsigned int r = z.i + 0x7fffu + ((z.i >> 16) & 1u);
  return (unsigned short)(r >> 16);
}
__device__ __forceinline__ unsigned int packbf(float a, float b) {
  return (unsigned int)f2b(a) | ((unsigned int)f2b(b) << 16);
}
__device__ __forceinline__ float lo16(unsigned int u) {
  union { unsigned int i; float f; } z; z.i = u << 16; return z.f;
}
__device__ __forceinline__ float hi16(unsigned int u) {
  union { unsigned int i; float f; } z; z.i = u & 0xffff0000u; return z.f;
}

// Build MFMA A-fragment weights (bf16) for both convs:
// wA[conv][tap][kb][mt][lane][j] = W[o=mt*16+(lane&15)][c=kb*32+(lane>>4)*8+j][tap]
// Also zero the reduction region (ws is 0xAA-poisoned before every call).
__global__ __launch_bounds__(256) void prep_kernel(
    const float* __restrict__ W1, const float* __restrict__ W2,
    unsigned short* __restrict__ wA, float* __restrict__ red)
{
  const int i = blockIdx.x * 256 + threadIdx.x;
  if (i < 73728) {
    const float* W = (i < 36864) ? W1 : W2;
    const int e = (i < 36864) ? i : (i - 36864);
    const int j    = e & 7;
    const int lane = (e >> 3) & 63;
    const int mt   = (e >> 9) & 3;
    const int kb   = (e >> 11) & 1;
    const int tap  = e >> 12;                 // 0..8 = dy*3+dx
    const int o = mt * 16 + (lane & 15);
    const int c = kb * 32 + ((lane >> 4) << 3) + j;
    wA[i] = f2b(W[o * 576 + c * 9 + tap]);
  } else if (i < 73728 + 33792) {
    red[i - 73728] = 0.0f;
  }
}

// Pass 1: per-pixel Q/K/V (1x1 conv), L2-normalize Q,K; write Qn (bf16 NCHW);
// accumulate k_sum, value_sum, agg_kv via LDS staging + global fp32 atomics.
__global__ __launch_bounds__(128) void qkv_kernel(
    const float* __restrict__ x,
    const float* __restrict__ Wq, const float* __restrict__ bq,
    const float* __restrict__ Wk, const float* __restrict__ bk,
    const float* __restrict__ Wv, const float* __restrict__ bv,
    unsigned short* __restrict__ Qn, float* __restrict__ red)
{
  __shared__ unsigned short sk[64 * SSTR];
  __shared__ unsigned short sv[64 * SSTR];
  const int b = blockIdx.y;
  const int t = threadIdx.x;
  const int ok0 = (t >> 3) << 2;   // 16 groups x 4 rows
  const int ov0 = (t & 7) << 3;    // 8 groups x 8 cols
  float agg[4][8];
#pragma unroll
  for (int i2 = 0; i2 < 4; ++i2)
#pragma unroll
    for (int j2 = 0; j2 < 8; ++j2) agg[i2][j2] = 0.f;
  float rsum = 0.f;

  for (int it = 0; it < 4; ++it) {
    const int n = (blockIdx.x << 9) + (it << 7) + t;
    const size_t base = (size_t)b * 64 * NPIX + n;
    float xv[64];
#pragma unroll
    for (int c = 0; c < 64; ++c) xv[c] = x[base + (size_t)c * NPIX];

#define MATVEC_STAGE(W, B, DST, SS)                                            \
    {                                                                          \
      SS = 0.f;                                                                \
      for (int o = 0; o < 64; o += 4) {                                        \
        float a0 = (B)[o],     a1 = (B)[o + 1];                                \
        float a2 = (B)[o + 2], a3 = (B)[o + 3];                                \
        _Pragma("unroll")                                                      \
        for (int c = 0; c < 64; ++c) {                                         \
          const float xc = xv[c];                                              \
          a0 = fmaf((W)[(o    ) * 64 + c], xc, a0);                            \
          a1 = fmaf((W)[(o + 1) * 64 + c], xc, a1);                            \
          a2 = fmaf((W)[(o + 2) * 64 + c], xc, a2);                            \
          a3 = fmaf((W)[(o + 3) * 64 + c], xc, a3);                            \
        }                                                                      \
        DST[(o    ) * SSTR + t] = f2b(a0);                                     \
        DST[(o + 1) * SSTR + t] = f2b(a1);                                     \
        DST[(o + 2) * SSTR + t] = f2b(a2);                                     \
        DST[(o + 3) * SSTR + t] = f2b(a3);                                     \
        SS = fmaf(a0, a0, SS); SS = fmaf(a1, a1, SS);                          \
        SS = fmaf(a2, a2, SS); SS = fmaf(a3, a3, SS);                          \
      }                                                                        \
    }

    float ssq, ssk, ssv;
    // Q staged into sv temporarily (own column), normalized, written to global
    MATVEC_STAGE(Wq, bq, sv, ssq);
    {
      const float rn = rsqrtf(ssq);
      for (int o = 0; o < 64; ++o)
        Qn[base + (size_t)o * NPIX] = f2b(b2f(sv[o * SSTR + t]) * rn);
    }
    // K staged into sk, normalized in place (own column only)
    MATVEC_STAGE(Wk, bk, sk, ssk);
    {
      const float rn = rsqrtf(ssk);
      for (int o = 0; o < 64; ++o)
        sk[o * SSTR + t] = f2b(b2f(sk[o * SSTR + t]) * rn);
    }
    // V staged into sv (overwrites Q staging; own column only)
    MATVEC_STAGE(Wv, bv, sv, ssv);
    (void)ssv;
    __syncthreads();
    // k_sum (wave 0) / value_sum (wave 1) partials
    {
      const unsigned short* row = (t < 64) ? (sk + t * SSTR) : (sv + (t - 64) * SSTR);
      float s2 = 0.f;
      for (int p = 0; p < 128; p += 2) {
        unsigned int u = *(const unsigned int*)(row + p);
        s2 += lo16(u) + hi16(u);
      }
      rsum += s2;
    }
    // agg_kv partial: each thread owns a 4x8 block of the 64x64 output
    for (int p = 0; p < 128; p += 2) {
      float k0[4], k1[4], v0[8], v1[8];
#pragma unroll
      for (int i2 = 0; i2 < 4; ++i2) {
        unsigned int u = *(const unsigned int*)(sk + (ok0 + i2) * SSTR + p);
        k0[i2] = lo16(u); k1[i2] = hi16(u);
      }
#pragma unroll
      for (int j2 = 0; j2 < 8; ++j2) {
        unsigned int u = *(const unsigned int*)(sv + (ov0 + j2) * SSTR + p);
        v0[j2] = lo16(u); v1[j2] = hi16(u);
      }
#pragma unroll
      for (int i2 = 0; i2 < 4; ++i2)
#pragma unroll
        for (int j2 = 0; j2 < 8; ++j2) {
          agg[i2][j2] = fmaf(k0[i2], v0[j2], agg[i2][j2]);
          agg[i2][j2] = fmaf(k1[i2], v1[j2], agg[i2][j2]);
        }
    }
    __syncthreads();
  }
  if (t < 64) atomicAdd(red + RED_KSUM + b * 64 + t, rsum);
  else        atomicAdd(red + RED_VSUM + b * 64 + (t - 64), rsum);
  float* aggb = red + RED_AGG + b * 4096;
#pragma unroll
  for (int i2 = 0; i2 < 4; ++i2)
#pragma unroll
    for (int j2 = 0; j2 < 8; ++j2)
      atomicAdd(aggb + (ok0 + i2) * 64 + (ov0 + j2), agg[i2][j2]);
}

// Pass 2: per pixel: denom, numerator = vsum + agg^T qn, *denom, then Wr 1x1.
// Output: NHWC bf16 (c contiguous per pixel) for the MFMA conv staging.
__global__ __launch_bounds__(256) void attn_kernel(
    const unsigned short* __restrict__ Qn,
    const float* __restrict__ Wr, const float* __restrict__ br,
    const float* __restrict__ red, unsigned short* __restrict__ attn)
{
  __shared__ __align__(16) unsigned short att[256 * 72];
  const int b = blockIdx.y;
  const int t = threadIdx.x;
  const int n = blockIdx.x * 256 + t;
  const size_t base = (size_t)b * 64 * NPIX + n;
  const float* ks  = red + RED_KSUM + b * 64;
  const float* vs  = red + RED_VSUM + b * 64;
  const float* agg = red + RED_AGG + b * 4096;
  float qn[64];
  float s = 0.f;
#pragma unroll
  for (int ok = 0; ok < 64; ++ok) {
    qn[ok] = b2f(Qn[base + (size_t)ok * NPIX]);
    s = fmaf(qn[ok], ks[ok] + 1e-6f, s);
  }
  const float denom = 1.0f / (65536.0f + s);
  float wvr[64];
  for (int ov = 0; ov < 64; ov += 4) {
    float a0 = vs[ov], a1 = vs[ov + 1], a2 = vs[ov + 2], a3 = vs[ov + 3];
#pragma unroll
    for (int ok = 0; ok < 64; ++ok) {
      const float qq = qn[ok];
      a0 = fmaf(agg[ok * 64 + ov    ], qq, a0);
      a1 = fmaf(agg[ok * 64 + ov + 1], qq, a1);
      a2 = fmaf(agg[ok * 64 + ov + 2], qq, a2);
      a3 = fmaf(agg[ok * 64 + ov + 3], qq, a3);
    }
    wvr[ov] = a0 * denom; wvr[ov + 1] = a1 * denom;
    wvr[ov + 2] = a2 * denom; wvr[ov + 3] = a3 * denom;
  }
  // Wr matvec; results packed 8-at-a-time into LDS [pixel][o] (pitch 72)
  for (int oc = 0; oc < 8; ++oc) {
    float rr[8];
#pragma unroll
    for (int r8 = 0; r8 < 8; r8 += 4) {
      const int o = oc * 8 + r8;
      float a0 = br[o], a1 = br[o + 1], a2 = br[o + 2], a3 = br[o + 3];
#pragma unroll
      for (int ov = 0; ov < 64; ++ov) {
        const float wv = wvr[ov];
        a0 = fmaf(Wr[(o    ) * 64 + ov], wv, a0);
        a1 = fmaf(Wr[(o + 1) * 64 + ov], wv, a1);
        a2 = fmaf(Wr[(o + 2) * 64 + ov], wv, a2);
        a3 = fmaf(Wr[(o + 3) * 64 + ov], wv, a3);
      }
      rr[r8] = a0; rr[r8 + 1] = a1; rr[r8 + 2] = a2; rr[r8 + 3] = a3;
    }
    uint4 pv;
    pv.x = packbf(rr[0], rr[1]); pv.y = packbf(rr[2], rr[3]);
    pv.z = packbf(rr[4], rr[5]); pv.w = packbf(rr[6], rr[7]);
    *(uint4*)(att + t * 72 + oc * 8) = pv;
  }
  __syncthreads();
  // dense NHWC store: wave w owns pixels w*64..w*64+63 (1KB contiguous/instr)
  const int w = t >> 6, lane = t & 63;
  const size_t wb = ((size_t)b * NPIX + (size_t)blockIdx.x * 256 + w * 64);
  const uint4* ra = (const uint4*)att + w * 64 * 9;
#pragma unroll
  for (int k = 0; k < 8; ++k) {
    const int p = (k << 3) + (lane >> 3);
    const int ch = lane & 7;
    *(uint4*)(attn + (wb + p) * 64 + ch * 8) = ra[p * 9 + ch];
  }
}

// 3x3 SAME conv, 64->64 ch, bf16 MFMA implicit GEMM.
// Tile: 32x(x) x 8(y) out pixels/block; LDS input tile 10x34 pixels, NHWC,
// c-pitch 72 shorts (16B-aligned b128 frags, 2-way-free read banks).
// Each wave: 64 o x 64 px via 4x4 tiles of mfma_f32_16x16x32_bf16.
// EPI=0: NHWC bf16 out (LDS transpose). EPI=1: fused *x+x, NCHW fp32 out.
template <int EPI>
__global__ __launch_bounds__(256, 3) void conv3_kernel(
    const unsigned short* __restrict__ in,   // NHWC bf16
    const unsigned short* __restrict__ wA,   // A-frag weights bf16
    const float* __restrict__ bias,
    const float* __restrict__ xin,           // NCHW fp32 (EPI=1)
    unsigned short* __restrict__ outh,       // NHWC bf16 (EPI=0)
    float* __restrict__ outf)                // NCHW fp32 (EPI=1)
{
  __shared__ __align__(16) unsigned short tile[10 * 34 * 72];
  const int bz = blockIdx.z;
  const int ty0 = blockIdx.y << 3;
  const int tx0 = blockIdx.x << 5;
  const int tid = threadIdx.x;
  const size_t nb = (size_t)bz * NPIX;

  // ---- stage NHWC tile (halo=1, zero-pad SAME) ----
  for (int s = tid; s < 2720; s += 256) {
    const int g = s & 7;
    const int pix = s >> 3;          // 0..339
    const int xx = pix % 34;
    const int row = pix / 34;
    const int gx = tx0 + xx - 1;
    const int gy = ty0 + row - 1;
    uint4 v = {0u, 0u, 0u, 0u};
    if ((unsigned)gx < 256u && (unsigned)gy < 256u)
      v = *(const uint4*)(in + ((nb + (gy << 8) + gx) << 6) + (g << 3));
    *(uint4*)(tile + pix * 72 + (g << 3)) = v;
  }
  __syncthreads();

  const int w = tid >> 6, lane = tid & 63, q = lane >> 4, l = lane & 15;
  f32x4 acc[4][4];
  {
#pragma unroll
    for (int mt = 0; mt < 4; ++mt) {
      const f32x4 bb = *(const f32x4*)(bias + mt * 16 + q * 4);
#pragma unroll
      for (int nt = 0; nt < 4; ++nt) acc[mt][nt] = bb;
    }
  }
  const short8* tp = (const short8*)tile;   // 72 shorts = 9 short8 per pixel
  for (int tap = 0; tap < 9; ++tap) {
    const int dy = tap / 3, dx = tap - dy * 3;
#pragma unroll
    for (int kb = 0; kb < 2; ++kb) {
      const unsigned short* wp = wA + (tap * 2 + kb) * 2048 + lane * 8;
      short8 af[4];
#pragma unroll
      for (int mt = 0; mt < 4; ++mt) af[mt] = *(const short8*)(wp + mt * 512);
      short8 bf[4];
#pragma unroll
      for (int nt = 0; nt < 4; ++nt) {
        const int yl = (w << 1) + (nt >> 1) + dy;           // 0..9
        const int xl = ((nt & 1) << 4) + l + dx;            // 0..33
        bf[nt] = tp[(yl * 34 + xl) * 9 + (kb << 2) + q];
      }
#pragma unroll
      for (int mt = 0; mt < 4; ++mt)
#pragma unroll
        for (int nt = 0; nt < 4; ++nt)
          acc[mt][nt] = __builtin_amdgcn_mfma_f32_16x16x32_bf16(
              af[mt], bf[nt], acc[mt][nt], 0, 0, 0);
    }
  }

  if (EPI == 0) {
    // NHWC bf16 epilogue: transpose C-frag -> [pixel][o] in LDS, dense store
    __syncthreads();                          // all waves done reading tile
    unsigned int* wreg = (unsigned int*)tile + w * 2304;   // 64 px * 36 uints
#pragma unroll
    for (int mt = 0; mt < 4; ++mt)
#pragma unroll
      for (int nt = 0; nt < 4; ++nt) {
        const int p = ((nt >> 1) << 5) + ((nt & 1) << 4) + l;
        unsigned int* dst = wreg + p * 36 + (mt << 3) + (q << 1);
        dst[0] = packbf(acc[mt][nt][0], acc[mt][nt][1]);
        dst[1] = packbf(acc[mt][nt][2], acc[mt][nt][3]);
      }
    __syncthreads();
    const uint4* rreg = (const uint4*)tile + w * 576;      // 64 px * 9 uint4
#pragma unroll
    for (int k = 0; k < 8; ++k) {
      const int p = (k << 3) + (lane >> 3);
      const int ch = lane & 7;
      const int gx = tx0 + (p & 31);
      const int gy = ty0 + (w << 1) + (p >> 5);
      *(uint4*)(outh + ((nb + (gy << 8) + gx) << 6) + (ch << 3)) =
          rreg[p * 9 + ch];
    }
  } else {
    // fused epilogue: out = conv*x + x, NCHW fp32
#pragma unroll
    for (int mt = 0; mt < 4; ++mt)
#pragma unroll
      for (int nt = 0; nt < 4; ++nt) {
        const int gx = tx0 + ((nt & 1) << 4) + l;
        const int gy = ty0 + (w << 1) + (nt >> 1);
#pragma unroll
        for (int r = 0; r < 4; ++r) {
          const int o = (mt << 4) + (q << 2) + r;
          const size_t idx = (((size_t)bz * 64 + o) << 16) + (gy << 8) + gx;
          const float xo = xin[idx];
          outf[idx] = fmaf(acc[mt][nt][r], xo, xo);
        }
      }
  }
}

extern "C" void kernel_launch(void* const* d_in, const int* in_sizes, int n_in,
                              void* d_out, int out_size, void* d_ws, size_t ws_size,
                              hipStream_t stream) {
  (void)in_sizes; (void)n_in; (void)out_size; (void)ws_size;
  const float* x  = (const float*)d_in[0];
  const float* Wq = (const float*)d_in[1];
  const float* bq = (const float*)d_in[2];
  const float* Wk = (const float*)d_in[3];
  const float* bk = (const float*)d_in[4];
  const float* Wv = (const float*)d_in[5];
  const float* bv = (const float*)d_in[6];
  const float* Wr = (const float*)d_in[7];
  const float* br = (const float*)d_in[8];
  const float* W1 = (const float*)d_in[9];
  const float* b1 = (const float*)d_in[10];
  const float* W2 = (const float*)d_in[11];
  const float* b2 = (const float*)d_in[12];

  // ws layout: wA1 [0,73728B) | wA2 [73728,147456B) | red 33792 fp32 | bufA
  unsigned short* wA1 = (unsigned short*)d_ws;
  unsigned short* wA2 = wA1 + 36864;
  float* red = (float*)((char*)d_ws + 147456);
  unsigned short* bufA = (unsigned short*)((char*)d_ws + 294912); // conv1 out, NHWC bf16
  // d_out (134MB fp32) doubles as scratch: first half = attn NHWC bf16,
  // second half = Qn NCHW bf16. Both fully consumed before conv2's final
  // fp32 NCHW write (stream-serialized).
  unsigned short* bufB = (unsigned short*)d_out;
  unsigned short* bufQ = (unsigned short*)((char*)d_out + 67108864);

  prep_kernel<<<420, 256, 0, stream>>>(W1, W2, wA1, red);
  qkv_kernel<<<dim3(128, 8), 128, 0, stream>>>(x, Wq, bq, Wk, bk, Wv, bv, bufQ, red);
  attn_kernel<<<dim3(256, 8), 256, 0, stream>>>(bufQ, Wr, br, red, bufB);
  conv3_kernel<0><<<dim3(8, 32, 8), 256, 0, stream>>>(
      bufB, wA1, b1, nullptr, bufA, nullptr);
  conv3_kernel<1><<<dim3(8, 32, 8), 256, 0, stream>>>(
      bufA, wA2, b2, x, nullptr, (float*)d_out);
}